// Round 15
// baseline (67.318 us; speedup 1.0000x reference)
//
#include <hip/hip_runtime.h>
#include <math.h>

#define BB 32
#define CC 128
#define HW 1024
#define NG 32
#define TPG 4096
#define QSZ ((size_t)BB * 4 * HW * 32)   // elems per Q/K/V bf16 buffer

typedef __attribute__((ext_vector_type(8))) short fragAB;
typedef __attribute__((ext_vector_type(4))) float fragC;
typedef __attribute__((ext_vector_type(8))) ushort ushort8v;

__device__ __forceinline__ ushort f2bf(float f) {
  union { float f; uint u; } v; v.f = f;
  uint r = v.u + 0x7FFFu + ((v.u >> 16) & 1u);
  return (ushort)(r >> 16);
}
__device__ __forceinline__ float bf2f(ushort u) {
  return __uint_as_float((uint)u << 16);
}
// pack two f32 -> two bf16 (truncation) in one v_perm_b32: (hi_bf16<<16)|lo_bf16
__device__ __forceinline__ uint pack2(float lo, float hi) {
  return __builtin_amdgcn_perm(__float_as_uint(hi), __float_as_uint(lo), 0x07060302u);
}
__device__ __forceinline__ float bflo(uint u) { return __uint_as_float(u << 16); }
__device__ __forceinline__ float bfhi(uint u) { return __uint_as_float(u & 0xffff0000u); }
// LDS swizzle (byte offsets), 128B rows, g = 16B granule 0..7
__device__ __forceinline__ int vswz(int row, int g) {
  return row * 128 + 16 * (g ^ (row & 7));
}

// ---------------- GroupNorm stats + x->bf16 cast (blocks 0..1023) + weight prep ----
__global__ __launch_bounds__(256) void gn_stats(const float* __restrict__ x,
    float2* __restrict__ stats, ushort* __restrict__ x16,
    const float* __restrict__ qkvw, const float* __restrict__ projw,
    ushort* __restrict__ wq16, ushort* __restrict__ wp16) {
  if (blockIdx.x >= 1024) {
    int idx = (blockIdx.x - 1024) * 256 + threadIdx.x;   // 0..65535
    if (idx < 49152) wq16[idx] = f2bf(qkvw[idx]);
    else             wp16[idx - 49152] = f2bf(projw[idx - 49152]);
    return;
  }
  int blk = blockIdx.x;          // b*NG + g
  int b = blk >> 5, g = blk & 31;
  const float4* xp4 = (const float4*)(x + ((size_t)(b * CC + g * 4)) * HW);
  ushort* xo = x16 + ((size_t)(b * CC + g * 4)) * HW;
  float s = 0.f, s2 = 0.f;
  #pragma unroll
  for (int i = 0; i < 4; ++i) {
    int idx = threadIdx.x + i * 256;
    float4 v = xp4[idx];
    s  += v.x + v.y + v.z + v.w;
    s2 += v.x * v.x + v.y * v.y + v.z * v.z + v.w * v.w;
    ushort4 u;
    u.x = f2bf(v.x); u.y = f2bf(v.y); u.z = f2bf(v.z); u.w = f2bf(v.w);
    *(ushort4*)&xo[idx * 4] = u;
  }
  #pragma unroll
  for (int off = 32; off; off >>= 1) {
    s  += __shfl_down(s, off, 64);
    s2 += __shfl_down(s2, off, 64);
  }
  __shared__ float ls[4], ls2[4];
  int lane = threadIdx.x & 63, wid = threadIdx.x >> 6;
  if (lane == 0) { ls[wid] = s; ls2[wid] = s2; }
  __syncthreads();
  if (threadIdx.x == 0) {
    float a  = ls[0] + ls[1] + ls[2] + ls[3];
    float a2 = ls2[0] + ls2[1] + ls2[2] + ls2[3];
    float mu = a * (1.f / TPG);
    float var = a2 * (1.f / TPG) - mu * mu;
    stats[blk] = make_float2(mu, rsqrtf(var + 1e-5f));
  }
}

// ---------------- MFMA GEMM: D[o,t] = sum_c W[o,c] * X[t,c] ----------------
// PROJ=0: grid (16,2,32). Stage ONCE from bf16 x16 with GN fused, then 3
//   o-blocks (2 heads) with ping-pong weight prefetch. Frag-linear Q/K/V out
//   (q pre-scaled (1/32)*log2e).
// PROJ=1: grid (16,1,32). Stage ONCE from X16 [b][t][c]; 2 o-blocks;
//   out fp32 = D + bias[o] + resid.
template<int PROJ>
__global__ __launch_bounds__(256) void mgemm(
    const ushort* __restrict__ W16, const ushort* __restrict__ X16,
    const ushort* __restrict__ x16, const float2* __restrict__ stats,
    const float* __restrict__ gw, const float* __restrict__ gb,
    ushort* __restrict__ Qb, float* __restrict__ out,
    const float* __restrict__ bias, const float* __restrict__ resid) {
  __shared__ ushort Xs[64 * 128];    // 16KB, XOR-swizzled byte ^= ((row&7)<<4)
  int b = blockIdx.z, t0 = blockIdx.x * 64;
  int tid = threadIdx.x;
  int lane = tid & 63, w = tid >> 6, lc = lane & 15, lg = lane >> 4;
  int wo = w >> 1, wt = w & 1;

  if constexpr (PROJ == 0) {
    // fused-GN staging from bf16 x16 [c][t] -> Xs bf16 [t][c] swizzled
    int tq = tid & 15, co = tid >> 4;     // t-quad (4t), c-oct (8c)
    const ushort* xb = x16 + (size_t)b * CC * HW + t0 + tq * 4;
    float wsc[8], bsc[8];
    {
      float2 s0 = stats[b * 32 + co * 2];
      float2 s1 = stats[b * 32 + co * 2 + 1];
      #pragma unroll
      for (int cc = 0; cc < 8; ++cc) {
        float rst = (cc < 4) ? s0.y : s1.y;
        float mu  = (cc < 4) ? s0.x : s1.x;
        float g = gw[co * 8 + cc];
        wsc[cc] = g * rst;
        bsc[cc] = gb[co * 8 + cc] - mu * wsc[cc];
      }
    }
    ushort4 uv[8];
    #pragma unroll
    for (int cc = 0; cc < 8; ++cc)
      uv[cc] = *(const ushort4*)&xb[(size_t)(co * 8 + cc) * HW];
    #pragma unroll
    for (int tt = 0; tt < 4; ++tt) {
      int row = tq * 4 + tt;
      ushort8v r;
      #pragma unroll
      for (int cc = 0; cc < 8; ++cc) {
        ushort e = (tt == 0) ? uv[cc].x : (tt == 1) ? uv[cc].y : (tt == 2) ? uv[cc].z : uv[cc].w;
        r[cc] = f2bf(bf2f(e) * wsc[cc] + bsc[cc]);
      }
      int byt = (row * 256 + co * 16) ^ ((row & 7) << 4);
      *(ushort8v*)((char*)Xs + byt) = r;
    }
  } else {
    const char* src = (const char*)(X16 + ((size_t)b * HW + t0) * CC);
    char* dst = (char*)Xs;
    #pragma unroll
    for (int it = 0; it < 4; ++it) {
      int flat = tid * 16 + it * 4096;
      uint4 v = *(const uint4*)(src + flat);
      *(uint4*)(dst + (flat ^ (((flat >> 8) & 7) << 4))) = v;
    }
  }
  __syncthreads();

  auto load_af = [&](fragAB af[2][4], int o0) {
    #pragma unroll
    for (int i = 0; i < 2; ++i)
      #pragma unroll
      for (int kc = 0; kc < 4; ++kc)
        af[i][kc] = *(const fragAB*)&W16[(size_t)(o0 + wo * 32 + i * 16 + lc) * 128 + kc * 32 + lg * 8];
  };

  auto kloop = [&](fragAB af[2][4], fragC acc[2][2]) {
    #pragma unroll
    for (int i = 0; i < 2; ++i)
      #pragma unroll
      for (int j = 0; j < 2; ++j)
        acc[i][j] = (fragC){0.f, 0.f, 0.f, 0.f};
    #pragma unroll
    for (int kc = 0; kc < 4; ++kc) {
      fragAB bf[2];
      #pragma unroll
      for (int j = 0; j < 2; ++j) {
        int row = wt * 32 + j * 16 + lc;
        int byt = (row * 256 + kc * 64 + lg * 16) ^ ((row & 7) << 4);
        bf[j] = *(const fragAB*)((const char*)Xs + byt);
      }
      #pragma unroll
      for (int i = 0; i < 2; ++i)
        #pragma unroll
        for (int j = 0; j < 2; ++j)
          acc[i][j] = __builtin_amdgcn_mfma_f32_16x16x32_bf16(af[i][kc], bf[j], acc[i][j], 0, 0, 0);
    }
  };

  if constexpr (PROJ == 0) {
    auto epi = [&](fragC acc[2][2], int o0) {
      #pragma unroll
      for (int i = 0; i < 2; ++i) {
        int ob = o0 + wo * 32 + i * 16;
        int blk = ob >> 5;
        int hh = blk / 3, kind = blk % 3;  // 0=q,1=k,2=v
        size_t bh = (size_t)b * 4 + hh;
        float sc = (kind == 0) ? (0.03125f * 1.44269504f) : 1.f;
        #pragma unroll
        for (int j = 0; j < 2; ++j) {
          if (kind < 2) {
            ushort* dst = (kind == 0) ? Qb : (Qb + QSZ);
            int s16 = (t0 >> 4) + wt * 2 + j;
            int eo = s16 * 512 + (((ob & 16) >> 3) + (lg >> 1)) * 128 + lc * 8 + (lg & 1) * 4;
            ushort4 rv;
            rv.x = f2bf(acc[i][j][0] * sc); rv.y = f2bf(acc[i][j][1] * sc);
            rv.z = f2bf(acc[i][j][2] * sc); rv.w = f2bf(acc[i][j][3] * sc);
            *(ushort4*)&dst[bh * 32768 + eo] = rv;
          } else {
            ushort* Vb = Qb + 2 * QSZ;
            int eo = (t0 >> 6) * 2048 + ((ob & 16) >> 4) * 1024
                   + (wt * 4 + j * 2 + (lc >> 3)) * 128 + (lc & 7);
            #pragma unroll
            for (int r = 0; r < 4; ++r)
              Vb[bh * 32768 + eo + (lg * 4 + r) * 8] = f2bf(acc[i][j][r]);
          }
        }
      }
    };

    int oy = blockIdx.y * 192;            // 3 o-blocks = 2 heads per block
    fragAB afA[2][4], afB[2][4];
    fragC acc[2][2];
    load_af(afA, oy);
    load_af(afB, oy + 64);                // in flight during first compute
    kloop(afA, acc);
    epi(acc, oy);
    load_af(afA, oy + 128);
    kloop(afB, acc);
    epi(acc, oy + 64);
    kloop(afA, acc);
    epi(acc, oy + 128);
  } else {
    auto epi = [&](fragC acc[2][2], int o0) {
      #pragma unroll
      for (int i = 0; i < 2; ++i)
        #pragma unroll
        for (int j = 0; j < 2; ++j) {
          int t = t0 + wt * 32 + j * 16 + lc;
          #pragma unroll
          for (int r = 0; r < 4; ++r) {
            int o = o0 + wo * 32 + i * 16 + lg * 4 + r;
            size_t idx = ((size_t)b * CC + o) * HW + t;
            out[idx] = acc[i][j][r] + bias[o] + resid[idx];
          }
        }
    };
    fragAB afA[2][4], afB[2][4];
    fragC acc[2][2];
    load_af(afA, 0);
    load_af(afB, 64);
    kloop(afA, acc);
    epi(acc, 0);
    kloop(afB, acc);
    epi(acc, 64);
  }
}

// ---------------- MFMA flash attention v10: ts-ping-pong Ps + 16KB-exact LDS ----
__global__ __launch_bounds__(256) void attn7(
    const ushort* __restrict__ Qb, const ushort* __restrict__ Kb,
    const ushort* __restrict__ Vb, ushort* __restrict__ ao16) {
  __shared__ char arena[16384];   // wave w: [w*4096, w*4096+4096) = Ps(ts0)|Ps(ts1)

  int tid = threadIdx.x;
  int w = tid >> 6, lane = tid & 63, lc = lane & 15, lg = lane >> 4;
  int lb = blockIdx.x;
  int gp = (lb & 7) * 256 + (lb >> 3);   // XCD swizzle: 16 bh per XCD
  int bh = gp >> 4, qp = gp & 15;
  int h = bh & 3, b = bh >> 2;
  int qt = qp * 2 + (w >> 1);            // q-tile 0..31
  int sh = w & 1;                        // s-half
  int t0 = qt * 32;

  const ushort* Qg = Qb + (size_t)bh * 32768 + (size_t)qt * 1024 + lane * 8;
  const ushort* Kg = Kb + (size_t)bh * 32768 + lane * 8;
  const ushort* Vg = Vb + (size_t)bh * 32768 + lane * 8;

  fragAB q0 = *(const fragAB*)&Qg[0];
  fragAB q1 = *(const fragAB*)&Qg[512];

  fragC a00 = {0.f,0.f,0.f,0.f}, a01 = {0.f,0.f,0.f,0.f};
  fragC a10 = {0.f,0.f,0.f,0.f}, a11 = {0.f,0.f,0.f,0.f};
  float l0 = 0.f, l1 = 0.f;
  char* wreg = arena + w * 4096;

  #pragma unroll 2
  for (int i = sh * 8; i < sh * 8 + 8; ++i) {
    const ushort* Kt = Kg + i * 2048;
    const ushort* Vt = Vg + i * 2048;
    fragAB kf[4], vf[4];
    #pragma unroll
    for (int j = 0; j < 4; ++j) kf[j] = *(const fragAB*)&Kt[j * 512];
    #pragma unroll
    for (int u = 0; u < 4; ++u) vf[u] = *(const fragAB*)&Vt[u * 512];  // u = cs*2+ks

    #pragma unroll
    for (int ts = 0; ts < 2; ++ts) {
      fragAB qf = ts ? q1 : q0;
      char* PsB = wreg + ts * 2048;        // ping-pong by ts
      fragC S[4];
      #pragma unroll
      for (int j = 0; j < 4; ++j) {
        fragC z = {0.f,0.f,0.f,0.f};
        S[j] = __builtin_amdgcn_mfma_f32_16x16x32_bf16(kf[j], qf, z, 0, 0, 0);
      }
      float rs = 0.f;
      #pragma unroll
      for (int j = 0; j < 4; ++j) {
        float p0 = __builtin_amdgcn_exp2f(S[j][0]), p1 = __builtin_amdgcn_exp2f(S[j][1]);
        float p2 = __builtin_amdgcn_exp2f(S[j][2]), p3 = __builtin_amdgcn_exp2f(S[j][3]);
        rs += (p0 + p1) + (p2 + p3);
        uint2 wv2;
        wv2.x = pack2(p0, p1);
        wv2.y = pack2(p2, p3);
        int g = j * 2 + (lg >> 1);
        *(uint2*)(PsB + lc * 128 + 16 * (g ^ (lc & 7)) + (lg & 1) * 8) = wv2;
      }
      if (ts) l1 += rs; else l0 += rs;
      fragC* aA = ts ? &a01 : &a00;
      fragC* aB = ts ? &a11 : &a10;
      fragAB bp0 = *(const fragAB*)(PsB + vswz(lc, lg));
      fragAB bp1 = *(const fragAB*)(PsB + vswz(lc, 4 + lg));
      *aA = __builtin_amdgcn_mfma_f32_16x16x32_bf16(vf[0], bp0, *aA, 0, 0, 0);
      *aA = __builtin_amdgcn_mfma_f32_16x16x32_bf16(vf[1], bp1, *aA, 0, 0, 0);
      *aB = __builtin_amdgcn_mfma_f32_16x16x32_bf16(vf[2], bp0, *aB, 0, 0, 0);
      *aB = __builtin_amdgcn_mfma_f32_16x16x32_bf16(vf[3], bp1, *aB, 0, 0, 0);
    }
  }

  // ---- combine: sh==1 packs partials (bf16) into its OWN dead Ps region ----
  if (sh == 1) {
    char* slot = wreg + lane * 40;       // 40B/lane: 4x uint2 accs + float2 l
    uint2 u;
    u.x = pack2(a00[0], a00[1]); u.y = pack2(a00[2], a00[3]);
    *(uint2*)(slot) = u;
    u.x = pack2(a10[0], a10[1]); u.y = pack2(a10[2], a10[3]);
    *(uint2*)(slot + 8) = u;
    u.x = pack2(a01[0], a01[1]); u.y = pack2(a01[2], a01[3]);
    *(uint2*)(slot + 16) = u;
    u.x = pack2(a11[0], a11[1]); u.y = pack2(a11[2], a11[3]);
    *(uint2*)(slot + 24) = u;
    *(float2*)(slot + 32) = make_float2(l0, l1);
  }
  __syncthreads();
  if (sh == 1) return;

  {
    const char* slot = arena + (w + 1) * 4096 + lane * 40;
    uint2 u0 = *(const uint2*)(slot);
    uint2 u1 = *(const uint2*)(slot + 8);
    uint2 u2 = *(const uint2*)(slot + 16);
    uint2 u3 = *(const uint2*)(slot + 24);
    float2 lv = *(const float2*)(slot + 32);
    a00[0] += bflo(u0.x); a00[1] += bfhi(u0.x); a00[2] += bflo(u0.y); a00[3] += bfhi(u0.y);
    a10[0] += bflo(u1.x); a10[1] += bfhi(u1.x); a10[2] += bflo(u1.y); a10[3] += bfhi(u1.y);
    a01[0] += bflo(u2.x); a01[1] += bfhi(u2.x); a01[2] += bflo(u2.y); a01[3] += bfhi(u2.y);
    a11[0] += bflo(u3.x); a11[1] += bfhi(u3.x); a11[2] += bflo(u3.y); a11[3] += bfhi(u3.y);
    l0 += lv.x; l1 += lv.y;
  }

  l0 += __shfl_xor(l0, 16); l0 += __shfl_xor(l0, 32);
  l1 += __shfl_xor(l1, 16); l1 += __shfl_xor(l1, 32);
  float il0 = 1.f / l0, il1 = 1.f / l1;

  // Ol [32 t][40] in own dead region (same-wave LDS -> no barrier) -> global
  ushort* Ol = (ushort*)wreg;
  uint2 u;
  u.x = pack2(a00[0] * il0, a00[1] * il0); u.y = pack2(a00[2] * il0, a00[3] * il0);
  *(uint2*)&Ol[lc * 40 + lg * 4] = u;
  u.x = pack2(a10[0] * il0, a10[1] * il0); u.y = pack2(a10[2] * il0, a10[3] * il0);
  *(uint2*)&Ol[lc * 40 + 16 + lg * 4] = u;
  u.x = pack2(a01[0] * il1, a01[1] * il1); u.y = pack2(a01[2] * il1, a01[3] * il1);
  *(uint2*)&Ol[(lc + 16) * 40 + lg * 4] = u;
  u.x = pack2(a11[0] * il1, a11[1] * il1); u.y = pack2(a11[2] * il1, a11[3] * il1);
  *(uint2*)&Ol[(lc + 16) * 40 + 16 + lg * 4] = u;

  int row = lane >> 1, half = lane & 1;
  uint4 v0 = *(uint4*)&Ol[row * 40 + half * 16];
  uint4 v1 = *(uint4*)&Ol[row * 40 + half * 16 + 8];
  ushort* dst = &ao16[((size_t)b * HW + t0 + row) * CC + h * 32 + half * 16];
  *(uint4*)dst = v0;
  *(uint4*)(dst + 8) = v1;
}

extern "C" void kernel_launch(void* const* d_in, const int* in_sizes, int n_in,
                              void* d_out, int out_size, void* d_ws, size_t ws_size,
                              hipStream_t stream) {
  (void)in_sizes; (void)n_in; (void)out_size; (void)ws_size;
  const float* x     = (const float*)d_in[0];
  const float* gw    = (const float*)d_in[1];
  const float* gb    = (const float*)d_in[2];
  const float* qkvw  = (const float*)d_in[3];
  const float* projw = (const float*)d_in[4];
  const float* projb = (const float*)d_in[5];
  float* out = (float*)d_out;

  char* wsb = (char*)d_ws;
  ushort* ao16 = (ushort*)wsb;                              // 8 MB (attn out)
  ushort* Qb   = (ushort*)(wsb + ((size_t)8 << 20));        // 8 MB (frag-linear)
  ushort* Kb   = Qb + QSZ;                                  // 8 MB (frag-linear)
  ushort* Vb   = Qb + 2 * QSZ;                              // 8 MB (frag-linear)
  ushort* wq16 = (ushort*)(wsb + ((size_t)32 << 20));       // 96 KB
  ushort* wp16 = (ushort*)(wsb + ((size_t)32 << 20) + (128 << 10)); // 32 KB
  float2* stats = (float2*)(wsb + ((size_t)32 << 20) + (256 << 10)); // 8 KB
  ushort* x16  = (ushort*)(wsb + ((size_t)34 << 20));       // 8 MB (raw bf16 x)

  gn_stats<<<dim3(BB * NG + 256), 256, 0, stream>>>(x, stats, x16, qkvw, projw, wq16, wp16);
  mgemm<0><<<dim3(16, 2, BB), 256, 0, stream>>>(wq16, nullptr, x16, stats, gw, gb,
                                                Qb, nullptr, nullptr, nullptr);
  attn7<<<dim3(2048), 256, 0, stream>>>(Qb, Kb, Vb, ao16);
  mgemm<1><<<dim3(16, 1, BB), 256, 0, stream>>>(wp16, ao16, nullptr, nullptr, nullptr, nullptr,
                                                nullptr, out, projb, x);
}

// Round 16
// 67.298 us; speedup vs baseline: 1.0003x; 1.0003x over previous
//
#include <hip/hip_runtime.h>
#include <math.h>

#define BB 32
#define CC 128
#define HW 1024
#define NG 32
#define TPG 4096
#define QSZ ((size_t)BB * 4 * HW * 32)   // elems per Q/K/V bf16 buffer

typedef __attribute__((ext_vector_type(8))) short fragAB;
typedef __attribute__((ext_vector_type(4))) float fragC;
typedef __attribute__((ext_vector_type(8))) ushort ushort8v;

__device__ __forceinline__ ushort f2bf(float f) {
  union { float f; uint u; } v; v.f = f;
  uint r = v.u + 0x7FFFu + ((v.u >> 16) & 1u);
  return (ushort)(r >> 16);
}
__device__ __forceinline__ float bf2f(ushort u) {
  return __uint_as_float((uint)u << 16);
}
// pack two f32 -> two bf16 (truncation) in one v_perm_b32: (hi_bf16<<16)|lo_bf16
__device__ __forceinline__ uint pack2(float lo, float hi) {
  return __builtin_amdgcn_perm(__float_as_uint(hi), __float_as_uint(lo), 0x07060302u);
}
__device__ __forceinline__ float bflo(uint u) { return __uint_as_float(u << 16); }
__device__ __forceinline__ float bfhi(uint u) { return __uint_as_float(u & 0xffff0000u); }
// LDS swizzle (byte offsets), 128B rows, g = 16B granule 0..7
__device__ __forceinline__ int vswz(int row, int g) {
  return row * 128 + 16 * (g ^ (row & 7));
}

// ---------------- GroupNorm stats + x->bf16 cast (blocks 0..1023) + weight prep ----
__global__ __launch_bounds__(256) void gn_stats(const float* __restrict__ x,
    float2* __restrict__ stats, ushort* __restrict__ x16,
    const float* __restrict__ qkvw, const float* __restrict__ projw,
    ushort* __restrict__ wq16, ushort* __restrict__ wp16) {
  if (blockIdx.x >= 1024) {
    int idx = (blockIdx.x - 1024) * 256 + threadIdx.x;   // 0..65535
    if (idx < 49152) wq16[idx] = f2bf(qkvw[idx]);
    else             wp16[idx - 49152] = f2bf(projw[idx - 49152]);
    return;
  }
  int blk = blockIdx.x;          // b*NG + g
  int b = blk >> 5, g = blk & 31;
  const float4* xp4 = (const float4*)(x + ((size_t)(b * CC + g * 4)) * HW);
  ushort* xo = x16 + ((size_t)(b * CC + g * 4)) * HW;
  float s = 0.f, s2 = 0.f;
  #pragma unroll
  for (int i = 0; i < 4; ++i) {
    int idx = threadIdx.x + i * 256;
    float4 v = xp4[idx];
    s  += v.x + v.y + v.z + v.w;
    s2 += v.x * v.x + v.y * v.y + v.z * v.z + v.w * v.w;
    ushort4 u;
    u.x = f2bf(v.x); u.y = f2bf(v.y); u.z = f2bf(v.z); u.w = f2bf(v.w);
    *(ushort4*)&xo[idx * 4] = u;
  }
  #pragma unroll
  for (int off = 32; off; off >>= 1) {
    s  += __shfl_down(s, off, 64);
    s2 += __shfl_down(s2, off, 64);
  }
  __shared__ float ls[4], ls2[4];
  int lane = threadIdx.x & 63, wid = threadIdx.x >> 6;
  if (lane == 0) { ls[wid] = s; ls2[wid] = s2; }
  __syncthreads();
  if (threadIdx.x == 0) {
    float a  = ls[0] + ls[1] + ls[2] + ls[3];
    float a2 = ls2[0] + ls2[1] + ls2[2] + ls2[3];
    float mu = a * (1.f / TPG);
    float var = a2 * (1.f / TPG) - mu * mu;
    stats[blk] = make_float2(mu, rsqrtf(var + 1e-5f));
  }
}

// ---------------- MFMA GEMM: D[o,t] = sum_c W[o,c] * X[t,c] ----------------
// PROJ=0: grid (16,1,32). Stage ONCE from bf16 x16 with GN fused, then ALL 6
//   o-blocks (4 heads) with ping-pong weight prefetch. Frag-linear Q/K/V out
//   (q pre-scaled (1/32)*log2e).
// PROJ=1: grid (16,1,32). Stage ONCE from X16 [b][t][c]; 2 o-blocks;
//   out fp32 = D + bias[o] + resid.
template<int PROJ>
__global__ __launch_bounds__(256) void mgemm(
    const ushort* __restrict__ W16, const ushort* __restrict__ X16,
    const ushort* __restrict__ x16, const float2* __restrict__ stats,
    const float* __restrict__ gw, const float* __restrict__ gb,
    ushort* __restrict__ Qb, float* __restrict__ out,
    const float* __restrict__ bias, const float* __restrict__ resid) {
  __shared__ ushort Xs[64 * 128];    // 16KB, XOR-swizzled byte ^= ((row&7)<<4)
  int b = blockIdx.z, t0 = blockIdx.x * 64;
  int tid = threadIdx.x;
  int lane = tid & 63, w = tid >> 6, lc = lane & 15, lg = lane >> 4;
  int wo = w >> 1, wt = w & 1;

  if constexpr (PROJ == 0) {
    // fused-GN staging from bf16 x16 [c][t] -> Xs bf16 [t][c] swizzled
    int tq = tid & 15, co = tid >> 4;     // t-quad (4t), c-oct (8c)
    const ushort* xb = x16 + (size_t)b * CC * HW + t0 + tq * 4;
    float wsc[8], bsc[8];
    {
      float2 s0 = stats[b * 32 + co * 2];
      float2 s1 = stats[b * 32 + co * 2 + 1];
      #pragma unroll
      for (int cc = 0; cc < 8; ++cc) {
        float rst = (cc < 4) ? s0.y : s1.y;
        float mu  = (cc < 4) ? s0.x : s1.x;
        float g = gw[co * 8 + cc];
        wsc[cc] = g * rst;
        bsc[cc] = gb[co * 8 + cc] - mu * wsc[cc];
      }
    }
    ushort4 uv[8];
    #pragma unroll
    for (int cc = 0; cc < 8; ++cc)
      uv[cc] = *(const ushort4*)&xb[(size_t)(co * 8 + cc) * HW];
    #pragma unroll
    for (int tt = 0; tt < 4; ++tt) {
      int row = tq * 4 + tt;
      ushort8v r;
      #pragma unroll
      for (int cc = 0; cc < 8; ++cc) {
        ushort e = (tt == 0) ? uv[cc].x : (tt == 1) ? uv[cc].y : (tt == 2) ? uv[cc].z : uv[cc].w;
        r[cc] = f2bf(bf2f(e) * wsc[cc] + bsc[cc]);
      }
      int byt = (row * 256 + co * 16) ^ ((row & 7) << 4);
      *(ushort8v*)((char*)Xs + byt) = r;
    }
  } else {
    const char* src = (const char*)(X16 + ((size_t)b * HW + t0) * CC);
    char* dst = (char*)Xs;
    #pragma unroll
    for (int it = 0; it < 4; ++it) {
      int flat = tid * 16 + it * 4096;
      uint4 v = *(const uint4*)(src + flat);
      *(uint4*)(dst + (flat ^ (((flat >> 8) & 7) << 4))) = v;
    }
  }
  __syncthreads();

  auto load_af = [&](fragAB af[2][4], int o0) {
    #pragma unroll
    for (int i = 0; i < 2; ++i)
      #pragma unroll
      for (int kc = 0; kc < 4; ++kc)
        af[i][kc] = *(const fragAB*)&W16[(size_t)(o0 + wo * 32 + i * 16 + lc) * 128 + kc * 32 + lg * 8];
  };

  auto kloop = [&](fragAB af[2][4], fragC acc[2][2]) {
    #pragma unroll
    for (int i = 0; i < 2; ++i)
      #pragma unroll
      for (int j = 0; j < 2; ++j)
        acc[i][j] = (fragC){0.f, 0.f, 0.f, 0.f};
    #pragma unroll
    for (int kc = 0; kc < 4; ++kc) {
      fragAB bf[2];
      #pragma unroll
      for (int j = 0; j < 2; ++j) {
        int row = wt * 32 + j * 16 + lc;
        int byt = (row * 256 + kc * 64 + lg * 16) ^ ((row & 7) << 4);
        bf[j] = *(const fragAB*)((const char*)Xs + byt);
      }
      #pragma unroll
      for (int i = 0; i < 2; ++i)
        #pragma unroll
        for (int j = 0; j < 2; ++j)
          acc[i][j] = __builtin_amdgcn_mfma_f32_16x16x32_bf16(af[i][kc], bf[j], acc[i][j], 0, 0, 0);
    }
  };

  if constexpr (PROJ == 0) {
    auto epi = [&](fragC acc[2][2], int o0) {
      #pragma unroll
      for (int i = 0; i < 2; ++i) {
        int ob = o0 + wo * 32 + i * 16;
        int blk = ob >> 5;
        int hh = blk / 3, kind = blk % 3;  // 0=q,1=k,2=v
        size_t bh = (size_t)b * 4 + hh;
        float sc = (kind == 0) ? (0.03125f * 1.44269504f) : 1.f;
        #pragma unroll
        for (int j = 0; j < 2; ++j) {
          if (kind < 2) {
            ushort* dst = (kind == 0) ? Qb : (Qb + QSZ);
            int s16 = (t0 >> 4) + wt * 2 + j;
            int eo = s16 * 512 + (((ob & 16) >> 3) + (lg >> 1)) * 128 + lc * 8 + (lg & 1) * 4;
            ushort4 rv;
            rv.x = f2bf(acc[i][j][0] * sc); rv.y = f2bf(acc[i][j][1] * sc);
            rv.z = f2bf(acc[i][j][2] * sc); rv.w = f2bf(acc[i][j][3] * sc);
            *(ushort4*)&dst[bh * 32768 + eo] = rv;
          } else {
            ushort* Vb = Qb + 2 * QSZ;
            int eo = (t0 >> 6) * 2048 + ((ob & 16) >> 4) * 1024
                   + (wt * 4 + j * 2 + (lc >> 3)) * 128 + (lc & 7);
            #pragma unroll
            for (int r = 0; r < 4; ++r)
              Vb[bh * 32768 + eo + (lg * 4 + r) * 8] = f2bf(acc[i][j][r]);
          }
        }
      }
    };

    // all 6 o-blocks (384 outputs) per block, single staging, af ping-pong
    fragAB afA[2][4], afB[2][4];
    fragC acc[2][2];
    load_af(afA, 0);
    load_af(afB, 64);
    kloop(afA, acc); epi(acc, 0);   load_af(afA, 128);
    kloop(afB, acc); epi(acc, 64);  load_af(afB, 192);
    kloop(afA, acc); epi(acc, 128); load_af(afA, 256);
    kloop(afB, acc); epi(acc, 192); load_af(afB, 320);
    kloop(afA, acc); epi(acc, 256);
    kloop(afB, acc); epi(acc, 320);
  } else {
    auto epi = [&](fragC acc[2][2], int o0) {
      #pragma unroll
      for (int i = 0; i < 2; ++i)
        #pragma unroll
        for (int j = 0; j < 2; ++j) {
          int t = t0 + wt * 32 + j * 16 + lc;
          #pragma unroll
          for (int r = 0; r < 4; ++r) {
            int o = o0 + wo * 32 + i * 16 + lg * 4 + r;
            size_t idx = ((size_t)b * CC + o) * HW + t;
            out[idx] = acc[i][j][r] + bias[o] + resid[idx];
          }
        }
    };
    fragAB afA[2][4], afB[2][4];
    fragC acc[2][2];
    load_af(afA, 0);
    load_af(afB, 64);
    kloop(afA, acc);
    epi(acc, 0);
    kloop(afB, acc);
    epi(acc, 64);
  }
}

// ---------------- MFMA flash attention v10: ts-ping-pong Ps + 16KB-exact LDS ----
__global__ __launch_bounds__(256) void attn7(
    const ushort* __restrict__ Qb, const ushort* __restrict__ Kb,
    const ushort* __restrict__ Vb, ushort* __restrict__ ao16) {
  __shared__ char arena[16384];   // wave w: [w*4096, w*4096+4096) = Ps(ts0)|Ps(ts1)

  int tid = threadIdx.x;
  int w = tid >> 6, lane = tid & 63, lc = lane & 15, lg = lane >> 4;
  int lb = blockIdx.x;
  int gp = (lb & 7) * 256 + (lb >> 3);   // XCD swizzle: 16 bh per XCD
  int bh = gp >> 4, qp = gp & 15;
  int h = bh & 3, b = bh >> 2;
  int qt = qp * 2 + (w >> 1);            // q-tile 0..31
  int sh = w & 1;                        // s-half
  int t0 = qt * 32;

  const ushort* Qg = Qb + (size_t)bh * 32768 + (size_t)qt * 1024 + lane * 8;
  const ushort* Kg = Kb + (size_t)bh * 32768 + lane * 8;
  const ushort* Vg = Vb + (size_t)bh * 32768 + lane * 8;

  fragAB q0 = *(const fragAB*)&Qg[0];
  fragAB q1 = *(const fragAB*)&Qg[512];

  fragC a00 = {0.f,0.f,0.f,0.f}, a01 = {0.f,0.f,0.f,0.f};
  fragC a10 = {0.f,0.f,0.f,0.f}, a11 = {0.f,0.f,0.f,0.f};
  float l0 = 0.f, l1 = 0.f;
  char* wreg = arena + w * 4096;

  for (int i = sh * 8; i < sh * 8 + 8; ++i) {
    const ushort* Kt = Kg + i * 2048;
    const ushort* Vt = Vg + i * 2048;
    fragAB kf[4], vf[4];
    #pragma unroll
    for (int j = 0; j < 4; ++j) kf[j] = *(const fragAB*)&Kt[j * 512];
    #pragma unroll
    for (int u = 0; u < 4; ++u) vf[u] = *(const fragAB*)&Vt[u * 512];  // u = cs*2+ks

    #pragma unroll
    for (int ts = 0; ts < 2; ++ts) {
      fragAB qf = ts ? q1 : q0;
      char* PsB = wreg + ts * 2048;        // ping-pong by ts
      fragC S[4];
      #pragma unroll
      for (int j = 0; j < 4; ++j) {
        fragC z = {0.f,0.f,0.f,0.f};
        S[j] = __builtin_amdgcn_mfma_f32_16x16x32_bf16(kf[j], qf, z, 0, 0, 0);
      }
      float rs = 0.f;
      #pragma unroll
      for (int j = 0; j < 4; ++j) {
        float p0 = __builtin_amdgcn_exp2f(S[j][0]), p1 = __builtin_amdgcn_exp2f(S[j][1]);
        float p2 = __builtin_amdgcn_exp2f(S[j][2]), p3 = __builtin_amdgcn_exp2f(S[j][3]);
        rs += (p0 + p1) + (p2 + p3);
        uint2 wv2;
        wv2.x = pack2(p0, p1);
        wv2.y = pack2(p2, p3);
        int g = j * 2 + (lg >> 1);
        *(uint2*)(PsB + lc * 128 + 16 * (g ^ (lc & 7)) + (lg & 1) * 8) = wv2;
      }
      if (ts) l1 += rs; else l0 += rs;
      fragC* aA = ts ? &a01 : &a00;
      fragC* aB = ts ? &a11 : &a10;
      fragAB bp0 = *(const fragAB*)(PsB + vswz(lc, lg));
      fragAB bp1 = *(const fragAB*)(PsB + vswz(lc, 4 + lg));
      *aA = __builtin_amdgcn_mfma_f32_16x16x32_bf16(vf[0], bp0, *aA, 0, 0, 0);
      *aA = __builtin_amdgcn_mfma_f32_16x16x32_bf16(vf[1], bp1, *aA, 0, 0, 0);
      *aB = __builtin_amdgcn_mfma_f32_16x16x32_bf16(vf[2], bp0, *aB, 0, 0, 0);
      *aB = __builtin_amdgcn_mfma_f32_16x16x32_bf16(vf[3], bp1, *aB, 0, 0, 0);
    }
  }

  // ---- combine: sh==1 packs partials (bf16) into its OWN dead Ps region ----
  if (sh == 1) {
    char* slot = wreg + lane * 40;       // 40B/lane: 4x uint2 accs + float2 l
    uint2 u;
    u.x = pack2(a00[0], a00[1]); u.y = pack2(a00[2], a00[3]);
    *(uint2*)(slot) = u;
    u.x = pack2(a10[0], a10[1]); u.y = pack2(a10[2], a10[3]);
    *(uint2*)(slot + 8) = u;
    u.x = pack2(a01[0], a01[1]); u.y = pack2(a01[2], a01[3]);
    *(uint2*)(slot + 16) = u;
    u.x = pack2(a11[0], a11[1]); u.y = pack2(a11[2], a11[3]);
    *(uint2*)(slot + 24) = u;
    *(float2*)(slot + 32) = make_float2(l0, l1);
  }
  __syncthreads();
  if (sh == 1) return;

  {
    const char* slot = arena + (w + 1) * 4096 + lane * 40;
    uint2 u0 = *(const uint2*)(slot);
    uint2 u1 = *(const uint2*)(slot + 8);
    uint2 u2 = *(const uint2*)(slot + 16);
    uint2 u3 = *(const uint2*)(slot + 24);
    float2 lv = *(const float2*)(slot + 32);
    a00[0] += bflo(u0.x); a00[1] += bfhi(u0.x); a00[2] += bflo(u0.y); a00[3] += bfhi(u0.y);
    a10[0] += bflo(u1.x); a10[1] += bfhi(u1.x); a10[2] += bflo(u1.y); a10[3] += bfhi(u1.y);
    a01[0] += bflo(u2.x); a01[1] += bfhi(u2.x); a01[2] += bflo(u2.y); a01[3] += bfhi(u2.y);
    a11[0] += bflo(u3.x); a11[1] += bfhi(u3.x); a11[2] += bflo(u3.y); a11[3] += bfhi(u3.y);
    l0 += lv.x; l1 += lv.y;
  }

  l0 += __shfl_xor(l0, 16); l0 += __shfl_xor(l0, 32);
  l1 += __shfl_xor(l1, 16); l1 += __shfl_xor(l1, 32);
  float il0 = 1.f / l0, il1 = 1.f / l1;

  // Ol [32 t][40] in own dead region (same-wave LDS -> no barrier) -> global
  ushort* Ol = (ushort*)wreg;
  uint2 u;
  u.x = pack2(a00[0] * il0, a00[1] * il0); u.y = pack2(a00[2] * il0, a00[3] * il0);
  *(uint2*)&Ol[lc * 40 + lg * 4] = u;
  u.x = pack2(a10[0] * il0, a10[1] * il0); u.y = pack2(a10[2] * il0, a10[3] * il0);
  *(uint2*)&Ol[lc * 40 + 16 + lg * 4] = u;
  u.x = pack2(a01[0] * il1, a01[1] * il1); u.y = pack2(a01[2] * il1, a01[3] * il1);
  *(uint2*)&Ol[(lc + 16) * 40 + lg * 4] = u;
  u.x = pack2(a11[0] * il1, a11[1] * il1); u.y = pack2(a11[2] * il1, a11[3] * il1);
  *(uint2*)&Ol[(lc + 16) * 40 + 16 + lg * 4] = u;

  int row = lane >> 1, half = lane & 1;
  uint4 v0 = *(uint4*)&Ol[row * 40 + half * 16];
  uint4 v1 = *(uint4*)&Ol[row * 40 + half * 16 + 8];
  ushort* dst = &ao16[((size_t)b * HW + t0 + row) * CC + h * 32 + half * 16];
  *(uint4*)dst = v0;
  *(uint4*)(dst + 8) = v1;
}

extern "C" void kernel_launch(void* const* d_in, const int* in_sizes, int n_in,
                              void* d_out, int out_size, void* d_ws, size_t ws_size,
                              hipStream_t stream) {
  (void)in_sizes; (void)n_in; (void)out_size; (void)ws_size;
  const float* x     = (const float*)d_in[0];
  const float* gw    = (const float*)d_in[1];
  const float* gb    = (const float*)d_in[2];
  const float* qkvw  = (const float*)d_in[3];
  const float* projw = (const float*)d_in[4];
  const float* projb = (const float*)d_in[5];
  float* out = (float*)d_out;

  char* wsb = (char*)d_ws;
  ushort* ao16 = (ushort*)wsb;                              // 8 MB (attn out)
  ushort* Qb   = (ushort*)(wsb + ((size_t)8 << 20));        // 8 MB (frag-linear)
  ushort* Kb   = Qb + QSZ;                                  // 8 MB (frag-linear)
  ushort* Vb   = Qb + 2 * QSZ;                              // 8 MB (frag-linear)
  ushort* wq16 = (ushort*)(wsb + ((size_t)32 << 20));       // 96 KB
  ushort* wp16 = (ushort*)(wsb + ((size_t)32 << 20) + (128 << 10)); // 32 KB
  float2* stats = (float2*)(wsb + ((size_t)32 << 20) + (256 << 10)); // 8 KB
  ushort* x16  = (ushort*)(wsb + ((size_t)34 << 20));       // 8 MB (raw bf16 x)

  gn_stats<<<dim3(BB * NG + 256), 256, 0, stream>>>(x, stats, x16, qkvw, projw, wq16, wp16);
  mgemm<0><<<dim3(16, 1, BB), 256, 0, stream>>>(wq16, nullptr, x16, stats, gw, gb,
                                                Qb, nullptr, nullptr, nullptr);
  attn7<<<dim3(2048), 256, 0, stream>>>(Qb, Kb, Vb, ao16);
  mgemm<1><<<dim3(16, 1, BB), 256, 0, stream>>>(wp16, ao16, nullptr, nullptr, nullptr, nullptr,
                                                nullptr, out, projb, x);
}

// Round 17
// 60.163 us; speedup vs baseline: 1.1189x; 1.1186x over previous
//
#include <hip/hip_runtime.h>
#include <math.h>

#define BB 32
#define CC 128
#define HW 1024
#define NG 32
#define TPG 4096
#define QSZ ((size_t)BB * 4 * HW * 32)   // elems per Q/K/V bf16 buffer

typedef __attribute__((ext_vector_type(8))) short fragAB;
typedef __attribute__((ext_vector_type(4))) float fragC;
typedef __attribute__((ext_vector_type(8))) ushort ushort8v;

__device__ __forceinline__ ushort f2bf(float f) {
  union { float f; uint u; } v; v.f = f;
  uint r = v.u + 0x7FFFu + ((v.u >> 16) & 1u);
  return (ushort)(r >> 16);
}
// pack two f32 -> two bf16 (truncation) in one v_perm_b32: (hi_bf16<<16)|lo_bf16
__device__ __forceinline__ uint pack2(float lo, float hi) {
  return __builtin_amdgcn_perm(__float_as_uint(hi), __float_as_uint(lo), 0x07060302u);
}
__device__ __forceinline__ float bflo(uint u) { return __uint_as_float(u << 16); }
__device__ __forceinline__ float bfhi(uint u) { return __uint_as_float(u & 0xffff0000u); }
// LDS swizzle (byte offsets), 128B rows, g = 16B granule 0..7
__device__ __forceinline__ int vswz(int row, int g) {
  return row * 128 + 16 * (g ^ (row & 7));
}

// ---------------- GroupNorm stats (blocks 0..1023) + weight bf16 prep (1024..1279) ----
__global__ __launch_bounds__(256) void gn_stats(const float* __restrict__ x,
    float2* __restrict__ stats, const float* __restrict__ qkvw,
    const float* __restrict__ projw, ushort* __restrict__ wq16,
    ushort* __restrict__ wp16) {
  if (blockIdx.x >= 1024) {
    int idx = (blockIdx.x - 1024) * 256 + threadIdx.x;   // 0..65535
    if (idx < 49152) wq16[idx] = f2bf(qkvw[idx]);
    else             wp16[idx - 49152] = f2bf(projw[idx - 49152]);
    return;
  }
  int blk = blockIdx.x;          // b*NG + g
  int b = blk >> 5, g = blk & 31;
  const float4* xp4 = (const float4*)(x + ((size_t)(b * CC + g * 4)) * HW);
  float s = 0.f, s2 = 0.f;
  #pragma unroll
  for (int i = 0; i < 4; ++i) {
    float4 v = xp4[threadIdx.x + i * 256];
    s  += v.x + v.y + v.z + v.w;
    s2 += v.x * v.x + v.y * v.y + v.z * v.z + v.w * v.w;
  }
  #pragma unroll
  for (int off = 32; off; off >>= 1) {
    s  += __shfl_down(s, off, 64);
    s2 += __shfl_down(s2, off, 64);
  }
  __shared__ float ls[4], ls2[4];
  int lane = threadIdx.x & 63, wid = threadIdx.x >> 6;
  if (lane == 0) { ls[wid] = s; ls2[wid] = s2; }
  __syncthreads();
  if (threadIdx.x == 0) {
    float a  = ls[0] + ls[1] + ls[2] + ls[3];
    float a2 = ls2[0] + ls2[1] + ls2[2] + ls2[3];
    float mu = a * (1.f / TPG);
    float var = a2 * (1.f / TPG) - mu * mu;
    stats[blk] = make_float2(mu, rsqrtf(var + 1e-5f));
  }
}

// ---------------- QKV MFMA GEMM: fused GN staging (fp32 x), 6 o-blocks/block ----
// Frag-linear Q/K/V out (q pre-scaled (1/32)*log2e). Grid (16,1,32).
__global__ __launch_bounds__(256) void mgemm_qkv(
    const ushort* __restrict__ W16, const float* __restrict__ xf,
    const float2* __restrict__ stats, const float* __restrict__ gw,
    const float* __restrict__ gb, ushort* __restrict__ Qb) {
  __shared__ ushort Xs[64 * 128];    // 16KB, XOR-swizzled byte ^= ((row&7)<<4)
  int b = blockIdx.z, t0 = blockIdx.x * 64;
  int tid = threadIdx.x;
  int lane = tid & 63, w = tid >> 6, lc = lane & 15, lg = lane >> 4;
  int wo = w >> 1, wt = w & 1;

  { // fused-GN staging: x fp32 [c][t] -> Xs bf16 [t][c] swizzled (once per block)
    int tq = tid & 15, co = tid >> 4;     // t-quad (4t), c-oct (8c)
    const float* xb = xf + (size_t)b * CC * HW + t0 + tq * 4;
    float wsc[8], bsc[8];
    {
      float2 s0 = stats[b * 32 + co * 2];
      float2 s1 = stats[b * 32 + co * 2 + 1];
      #pragma unroll
      for (int cc = 0; cc < 8; ++cc) {
        float rst = (cc < 4) ? s0.y : s1.y;
        float mu  = (cc < 4) ? s0.x : s1.x;
        float g = gw[co * 8 + cc];
        wsc[cc] = g * rst;
        bsc[cc] = gb[co * 8 + cc] - mu * wsc[cc];
      }
    }
    union { float4 v; float f[4]; } vv[8];
    #pragma unroll
    for (int cc = 0; cc < 8; ++cc)
      vv[cc].v = *(const float4*)&xb[(size_t)(co * 8 + cc) * HW];
    #pragma unroll
    for (int tt = 0; tt < 4; ++tt) {
      int row = tq * 4 + tt;
      ushort8v r;
      #pragma unroll
      for (int cc = 0; cc < 8; ++cc)
        r[cc] = f2bf(vv[cc].f[tt] * wsc[cc] + bsc[cc]);
      int byt = (row * 256 + co * 16) ^ ((row & 7) << 4);
      *(ushort8v*)((char*)Xs + byt) = r;
    }
  }
  __syncthreads();

  auto load_af = [&](fragAB af[2][4], int o0) {
    #pragma unroll
    for (int i = 0; i < 2; ++i)
      #pragma unroll
      for (int kc = 0; kc < 4; ++kc)
        af[i][kc] = *(const fragAB*)&W16[(size_t)(o0 + wo * 32 + i * 16 + lc) * 128 + kc * 32 + lg * 8];
  };
  auto kloop = [&](fragAB af[2][4], fragC acc[2][2]) {
    #pragma unroll
    for (int i = 0; i < 2; ++i)
      #pragma unroll
      for (int j = 0; j < 2; ++j)
        acc[i][j] = (fragC){0.f, 0.f, 0.f, 0.f};
    #pragma unroll
    for (int kc = 0; kc < 4; ++kc) {
      fragAB bf[2];
      #pragma unroll
      for (int j = 0; j < 2; ++j) {
        int row = wt * 32 + j * 16 + lc;
        int byt = (row * 256 + kc * 64 + lg * 16) ^ ((row & 7) << 4);
        bf[j] = *(const fragAB*)((const char*)Xs + byt);
      }
      #pragma unroll
      for (int i = 0; i < 2; ++i)
        #pragma unroll
        for (int j = 0; j < 2; ++j)
          acc[i][j] = __builtin_amdgcn_mfma_f32_16x16x32_bf16(af[i][kc], bf[j], acc[i][j], 0, 0, 0);
    }
  };
  auto epi = [&](fragC acc[2][2], int o0) {
    #pragma unroll
    for (int i = 0; i < 2; ++i) {
      int ob = o0 + wo * 32 + i * 16;
      int blk = ob >> 5;
      int hh = blk / 3, kind = blk % 3;  // 0=q,1=k,2=v
      size_t bh = (size_t)b * 4 + hh;
      float sc = (kind == 0) ? (0.03125f * 1.44269504f) : 1.f;
      #pragma unroll
      for (int j = 0; j < 2; ++j) {
        if (kind < 2) {
          ushort* dst = (kind == 0) ? Qb : (Qb + QSZ);
          int s16 = (t0 >> 4) + wt * 2 + j;
          int eo = s16 * 512 + (((ob & 16) >> 3) + (lg >> 1)) * 128 + lc * 8 + (lg & 1) * 4;
          ushort4 rv;
          rv.x = f2bf(acc[i][j][0] * sc); rv.y = f2bf(acc[i][j][1] * sc);
          rv.z = f2bf(acc[i][j][2] * sc); rv.w = f2bf(acc[i][j][3] * sc);
          *(ushort4*)&dst[bh * 32768 + eo] = rv;
        } else {
          ushort* Vb = Qb + 2 * QSZ;
          int eo = (t0 >> 6) * 2048 + ((ob & 16) >> 4) * 1024
                 + (wt * 4 + j * 2 + (lc >> 3)) * 128 + (lc & 7);
          #pragma unroll
          for (int r = 0; r < 4; ++r)
            Vb[bh * 32768 + eo + (lg * 4 + r) * 8] = f2bf(acc[i][j][r]);
        }
      }
    }
  };

  fragAB afA[2][4], afB[2][4];
  fragC acc[2][2];
  load_af(afA, 0);
  load_af(afB, 64);
  kloop(afA, acc); epi(acc, 0);   load_af(afA, 128);
  kloop(afB, acc); epi(acc, 64);  load_af(afB, 192);
  kloop(afA, acc); epi(acc, 128); load_af(afA, 256);
  kloop(afB, acc); epi(acc, 192); load_af(afB, 320);
  kloop(afA, acc); epi(acc, 256);
  kloop(afB, acc); epi(acc, 320);
}

// ---------------- Fused attention + proj: attn8 ----------------
// 512 thr = 8 waves = 4 heads x 2 s-halves; 32 q per block; grid (b x qt)=1024.
// Attn: frag-linear K/V direct global, static exp2 softmax, wave-private Ps.
// Combine per head-pair (packed bf16 in dead Ps), O -> LDS [32][136], then all
// 8 waves run proj GEMM (128o x 32t, k=128) with bias + fp32 residual epilogue.
__global__ __launch_bounds__(512) void attn8(
    const ushort* __restrict__ Qb, const ushort* __restrict__ Kb,
    const ushort* __restrict__ Vb, const ushort* __restrict__ wp16,
    const float* __restrict__ bias, const float* __restrict__ resid,
    float* __restrict__ out) {
  __shared__ char arena[27136];
  // [0,16384): Ps per wave 2048B (combine slots overlap sh==1 regions)
  // [16384,18432): l partials, 4 heads x 64 lanes x float2
  // [18432,27136): Olds [32][136] ushort

  int tid = threadIdx.x;
  int w = tid >> 6, lane = tid & 63, lc = lane & 15, lg = lane >> 4;
  int lb = blockIdx.x;
  int gp = (lb & 7) * 128 + (lb >> 3);   // XCD swizzle: 4 b per XCD
  int b = gp >> 5, qt = gp & 31;
  int h = w >> 1, sh = w & 1;
  int bh = b * 4 + h;
  int t0 = qt * 32;

  const ushort* Qg = Qb + (size_t)bh * 32768 + (size_t)qt * 1024 + lane * 8;
  const ushort* Kg = Kb + (size_t)bh * 32768 + lane * 8;
  const ushort* Vg = Vb + (size_t)bh * 32768 + lane * 8;

  fragAB q0 = *(const fragAB*)&Qg[0];
  fragAB q1 = *(const fragAB*)&Qg[512];

  fragC a00 = {0.f,0.f,0.f,0.f}, a01 = {0.f,0.f,0.f,0.f};
  fragC a10 = {0.f,0.f,0.f,0.f}, a11 = {0.f,0.f,0.f,0.f};
  float l0 = 0.f, l1 = 0.f;
  char* PsB = arena + w * 2048;

  for (int i = sh * 8; i < sh * 8 + 8; ++i) {
    const ushort* Kt = Kg + i * 2048;
    const ushort* Vt = Vg + i * 2048;
    fragAB kf[4], vf[4];
    #pragma unroll
    for (int j = 0; j < 4; ++j) kf[j] = *(const fragAB*)&Kt[j * 512];
    #pragma unroll
    for (int u = 0; u < 4; ++u) vf[u] = *(const fragAB*)&Vt[u * 512];  // u = cs*2+ks

    #pragma unroll
    for (int ts = 0; ts < 2; ++ts) {
      fragAB qf = ts ? q1 : q0;
      fragC S[4];
      #pragma unroll
      for (int j = 0; j < 4; ++j) {
        fragC z = {0.f,0.f,0.f,0.f};
        S[j] = __builtin_amdgcn_mfma_f32_16x16x32_bf16(kf[j], qf, z, 0, 0, 0);
      }
      float rs = 0.f;
      #pragma unroll
      for (int j = 0; j < 4; ++j) {
        float p0 = __builtin_amdgcn_exp2f(S[j][0]), p1 = __builtin_amdgcn_exp2f(S[j][1]);
        float p2 = __builtin_amdgcn_exp2f(S[j][2]), p3 = __builtin_amdgcn_exp2f(S[j][3]);
        rs += (p0 + p1) + (p2 + p3);
        uint2 wv2;
        wv2.x = pack2(p0, p1);
        wv2.y = pack2(p2, p3);
        int g = j * 2 + (lg >> 1);
        *(uint2*)(PsB + lc * 128 + 16 * (g ^ (lc & 7)) + (lg & 1) * 8) = wv2;
      }
      if (ts) l1 += rs; else l0 += rs;
      fragC* aA = ts ? &a01 : &a00;
      fragC* aB = ts ? &a11 : &a10;
      fragAB bp0 = *(const fragAB*)(PsB + vswz(lc, lg));
      fragAB bp1 = *(const fragAB*)(PsB + vswz(lc, 4 + lg));
      *aA = __builtin_amdgcn_mfma_f32_16x16x32_bf16(vf[0], bp0, *aA, 0, 0, 0);
      *aA = __builtin_amdgcn_mfma_f32_16x16x32_bf16(vf[1], bp1, *aA, 0, 0, 0);
      *aB = __builtin_amdgcn_mfma_f32_16x16x32_bf16(vf[2], bp0, *aB, 0, 0, 0);
      *aB = __builtin_amdgcn_mfma_f32_16x16x32_bf16(vf[3], bp1, *aB, 0, 0, 0);
    }
  }

  // ---- combine: sh==1 packs acc partials (bf16, 32B/lane) into OWN dead Ps;
  //      l partials into the l-area ----
  float2* lpart = (float2*)(arena + 16384);
  if (sh == 1) {
    char* slot = PsB + lane * 32;
    uint2 u;
    u.x = pack2(a00[0], a00[1]); u.y = pack2(a00[2], a00[3]);
    *(uint2*)(slot) = u;
    u.x = pack2(a10[0], a10[1]); u.y = pack2(a10[2], a10[3]);
    *(uint2*)(slot + 8) = u;
    u.x = pack2(a01[0], a01[1]); u.y = pack2(a01[2], a01[3]);
    *(uint2*)(slot + 16) = u;
    u.x = pack2(a11[0], a11[1]); u.y = pack2(a11[2], a11[3]);
    *(uint2*)(slot + 24) = u;
    lpart[h * 64 + lane] = make_float2(l0, l1);
  }
  __syncthreads();

  ushort* Olds = (ushort*)(arena + 18432);   // [32][136]
  if (sh == 0) {
    const char* slot = arena + (w + 1) * 2048 + lane * 32;
    uint2 u0 = *(const uint2*)(slot);
    uint2 u1 = *(const uint2*)(slot + 8);
    uint2 u2 = *(const uint2*)(slot + 16);
    uint2 u3 = *(const uint2*)(slot + 24);
    float2 lv = lpart[h * 64 + lane];
    a00[0] += bflo(u0.x); a00[1] += bfhi(u0.x); a00[2] += bflo(u0.y); a00[3] += bfhi(u0.y);
    a10[0] += bflo(u1.x); a10[1] += bfhi(u1.x); a10[2] += bflo(u1.y); a10[3] += bfhi(u1.y);
    a01[0] += bflo(u2.x); a01[1] += bfhi(u2.x); a01[2] += bflo(u2.y); a01[3] += bfhi(u2.y);
    a11[0] += bflo(u3.x); a11[1] += bfhi(u3.x); a11[2] += bflo(u3.y); a11[3] += bfhi(u3.y);
    l0 += lv.x; l1 += lv.y;

    l0 += __shfl_xor(l0, 16); l0 += __shfl_xor(l0, 32);
    l1 += __shfl_xor(l1, 16); l1 += __shfl_xor(l1, 32);
    float il0 = 1.f / l0, il1 = 1.f / l1;

    // O (bf16 normalized) -> Olds rows lc / lc+16, cols h*32 + {lg*4, 16+lg*4}
    int cb = h * 32;
    uint2 u;
    u.x = pack2(a00[0] * il0, a00[1] * il0); u.y = pack2(a00[2] * il0, a00[3] * il0);
    *(uint2*)&Olds[lc * 136 + cb + lg * 4] = u;
    u.x = pack2(a10[0] * il0, a10[1] * il0); u.y = pack2(a10[2] * il0, a10[3] * il0);
    *(uint2*)&Olds[lc * 136 + cb + 16 + lg * 4] = u;
    u.x = pack2(a01[0] * il1, a01[1] * il1); u.y = pack2(a01[2] * il1, a01[3] * il1);
    *(uint2*)&Olds[(lc + 16) * 136 + cb + lg * 4] = u;
    u.x = pack2(a11[0] * il1, a11[1] * il1); u.y = pack2(a11[2] * il1, a11[3] * il1);
    *(uint2*)&Olds[(lc + 16) * 136 + cb + 16 + lg * 4] = u;
  }
  __syncthreads();

  // ---- proj GEMM: out[o,t] = sum_c wp[o,c] * O[t,c] + bias[o] + resid ----
  // wave w owns o rows [16w, 16w+16)
  fragC pacc[2] = {{0.f,0.f,0.f,0.f}, {0.f,0.f,0.f,0.f}};
  #pragma unroll
  for (int kc = 0; kc < 4; ++kc) {
    fragAB af = *(const fragAB*)&wp16[(size_t)(16 * w + lc) * 128 + kc * 32 + lg * 8];
    #pragma unroll
    for (int j = 0; j < 2; ++j) {
      fragAB bf = *(const fragAB*)&Olds[(j * 16 + lc) * 136 + kc * 32 + lg * 8];
      pacc[j] = __builtin_amdgcn_mfma_f32_16x16x32_bf16(af, bf, pacc[j], 0, 0, 0);
    }
  }
  #pragma unroll
  for (int j = 0; j < 2; ++j) {
    int t = t0 + j * 16 + lc;
    #pragma unroll
    for (int r = 0; r < 4; ++r) {
      int o = 16 * w + lg * 4 + r;
      size_t idx = ((size_t)b * CC + o) * HW + t;
      out[idx] = pacc[j][r] + bias[o] + resid[idx];
    }
  }
}

extern "C" void kernel_launch(void* const* d_in, const int* in_sizes, int n_in,
                              void* d_out, int out_size, void* d_ws, size_t ws_size,
                              hipStream_t stream) {
  (void)in_sizes; (void)n_in; (void)out_size; (void)ws_size;
  const float* x     = (const float*)d_in[0];
  const float* gw    = (const float*)d_in[1];
  const float* gb    = (const float*)d_in[2];
  const float* qkvw  = (const float*)d_in[3];
  const float* projw = (const float*)d_in[4];
  const float* projb = (const float*)d_in[5];
  float* out = (float*)d_out;

  char* wsb = (char*)d_ws;
  ushort* Qb   = (ushort*)(wsb + ((size_t)8 << 20));        // 8 MB (frag-linear)
  ushort* Kb   = Qb + QSZ;                                  // 8 MB (frag-linear)
  ushort* Vb   = Qb + 2 * QSZ;                              // 8 MB (frag-linear)
  ushort* wq16 = (ushort*)(wsb + ((size_t)32 << 20));       // 96 KB
  ushort* wp16 = (ushort*)(wsb + ((size_t)32 << 20) + (128 << 10)); // 32 KB
  float2* stats = (float2*)(wsb + ((size_t)32 << 20) + (256 << 10)); // 8 KB

  gn_stats<<<dim3(BB * NG + 256), 256, 0, stream>>>(x, stats, qkvw, projw, wq16, wp16);
  mgemm_qkv<<<dim3(16, 1, BB), 256, 0, stream>>>(wq16, x, stats, gw, gb, Qb);
  attn8<<<dim3(1024), 512, 0, stream>>>(Qb, Kb, Vb, wp16, projb, x, out);
}

// Round 18
// 58.420 us; speedup vs baseline: 1.1523x; 1.0298x over previous
//
#include <hip/hip_runtime.h>
#include <math.h>

#define BB 32
#define CC 128
#define HW 1024
#define NG 32
#define TPG 4096
#define QSZ ((size_t)BB * 4 * HW * 32)   // elems per Q/K/V bf16 buffer

typedef __attribute__((ext_vector_type(8))) short fragAB;
typedef __attribute__((ext_vector_type(4))) float fragC;
typedef __attribute__((ext_vector_type(8))) ushort ushort8v;

__device__ __forceinline__ ushort f2bf(float f) {
  union { float f; uint u; } v; v.f = f;
  uint r = v.u + 0x7FFFu + ((v.u >> 16) & 1u);
  return (ushort)(r >> 16);
}
// pack two f32 -> two bf16 (truncation) in one v_perm_b32: (hi_bf16<<16)|lo_bf16
__device__ __forceinline__ uint pack2(float lo, float hi) {
  return __builtin_amdgcn_perm(__float_as_uint(hi), __float_as_uint(lo), 0x07060302u);
}
// LDS swizzle (byte offsets), 128B rows, g = 16B granule 0..7
__device__ __forceinline__ int vswz(int row, int g) {
  return row * 128 + 16 * (g ^ (row & 7));
}

// ---------------- GroupNorm stats (blocks 0..1023) + weight bf16 prep (1024..1279) ----
__global__ __launch_bounds__(256) void gn_stats(const float* __restrict__ x,
    float2* __restrict__ stats, const float* __restrict__ qkvw,
    const float* __restrict__ projw, ushort* __restrict__ wq16,
    ushort* __restrict__ wp16) {
  if (blockIdx.x >= 1024) {
    int idx = (blockIdx.x - 1024) * 256 + threadIdx.x;   // 0..65535
    if (idx < 49152) wq16[idx] = f2bf(qkvw[idx]);
    else             wp16[idx - 49152] = f2bf(projw[idx - 49152]);
    return;
  }
  int blk = blockIdx.x;          // b*NG + g
  int b = blk >> 5, g = blk & 31;
  const float4* xp4 = (const float4*)(x + ((size_t)(b * CC + g * 4)) * HW);
  float s = 0.f, s2 = 0.f;
  #pragma unroll
  for (int i = 0; i < 4; ++i) {
    float4 v = xp4[threadIdx.x + i * 256];
    s  += v.x + v.y + v.z + v.w;
    s2 += v.x * v.x + v.y * v.y + v.z * v.z + v.w * v.w;
  }
  #pragma unroll
  for (int off = 32; off; off >>= 1) {
    s  += __shfl_down(s, off, 64);
    s2 += __shfl_down(s2, off, 64);
  }
  __shared__ float ls[4], ls2[4];
  int lane = threadIdx.x & 63, wid = threadIdx.x >> 6;
  if (lane == 0) { ls[wid] = s; ls2[wid] = s2; }
  __syncthreads();
  if (threadIdx.x == 0) {
    float a  = ls[0] + ls[1] + ls[2] + ls[3];
    float a2 = ls2[0] + ls2[1] + ls2[2] + ls2[3];
    float mu = a * (1.f / TPG);
    float var = a2 * (1.f / TPG) - mu * mu;
    stats[blk] = make_float2(mu, rsqrtf(var + 1e-5f));
  }
}

// ---------------- QKV MFMA GEMM: fused GN staging (fp32 x), 6 o-blocks/block ----
// Frag-linear Q/K/V out (q pre-scaled (1/32)*log2e). Grid (16,1,32).
__global__ __launch_bounds__(256) void mgemm_qkv(
    const ushort* __restrict__ W16, const float* __restrict__ xf,
    const float2* __restrict__ stats, const float* __restrict__ gw,
    const float* __restrict__ gb, ushort* __restrict__ Qb) {
  __shared__ ushort Xs[64 * 128];    // 16KB, XOR-swizzled byte ^= ((row&7)<<4)
  int b = blockIdx.z, t0 = blockIdx.x * 64;
  int tid = threadIdx.x;
  int lane = tid & 63, w = tid >> 6, lc = lane & 15, lg = lane >> 4;
  int wo = w >> 1, wt = w & 1;

  { // fused-GN staging: x fp32 [c][t] -> Xs bf16 [t][c] swizzled (once per block)
    int tq = tid & 15, co = tid >> 4;     // t-quad (4t), c-oct (8c)
    const float* xb = xf + (size_t)b * CC * HW + t0 + tq * 4;
    float wsc[8], bsc[8];
    {
      float2 s0 = stats[b * 32 + co * 2];
      float2 s1 = stats[b * 32 + co * 2 + 1];
      #pragma unroll
      for (int cc = 0; cc < 8; ++cc) {
        float rst = (cc < 4) ? s0.y : s1.y;
        float mu  = (cc < 4) ? s0.x : s1.x;
        float g = gw[co * 8 + cc];
        wsc[cc] = g * rst;
        bsc[cc] = gb[co * 8 + cc] - mu * wsc[cc];
      }
    }
    union { float4 v; float f[4]; } vv[8];
    #pragma unroll
    for (int cc = 0; cc < 8; ++cc)
      vv[cc].v = *(const float4*)&xb[(size_t)(co * 8 + cc) * HW];
    #pragma unroll
    for (int tt = 0; tt < 4; ++tt) {
      int row = tq * 4 + tt;
      ushort8v r;
      #pragma unroll
      for (int cc = 0; cc < 8; ++cc)
        r[cc] = f2bf(vv[cc].f[tt] * wsc[cc] + bsc[cc]);
      int byt = (row * 256 + co * 16) ^ ((row & 7) << 4);
      *(ushort8v*)((char*)Xs + byt) = r;
    }
  }
  __syncthreads();

  auto load_af = [&](fragAB af[2][4], int o0) {
    #pragma unroll
    for (int i = 0; i < 2; ++i)
      #pragma unroll
      for (int kc = 0; kc < 4; ++kc)
        af[i][kc] = *(const fragAB*)&W16[(size_t)(o0 + wo * 32 + i * 16 + lc) * 128 + kc * 32 + lg * 8];
  };
  auto kloop = [&](fragAB af[2][4], fragC acc[2][2]) {
    #pragma unroll
    for (int i = 0; i < 2; ++i)
      #pragma unroll
      for (int j = 0; j < 2; ++j)
        acc[i][j] = (fragC){0.f, 0.f, 0.f, 0.f};
    #pragma unroll
    for (int kc = 0; kc < 4; ++kc) {
      fragAB bf[2];
      #pragma unroll
      for (int j = 0; j < 2; ++j) {
        int row = wt * 32 + j * 16 + lc;
        int byt = (row * 256 + kc * 64 + lg * 16) ^ ((row & 7) << 4);
        bf[j] = *(const fragAB*)((const char*)Xs + byt);
      }
      #pragma unroll
      for (int i = 0; i < 2; ++i)
        #pragma unroll
        for (int j = 0; j < 2; ++j)
          acc[i][j] = __builtin_amdgcn_mfma_f32_16x16x32_bf16(af[i][kc], bf[j], acc[i][j], 0, 0, 0);
    }
  };
  auto epi = [&](fragC acc[2][2], int o0) {
    #pragma unroll
    for (int i = 0; i < 2; ++i) {
      int ob = o0 + wo * 32 + i * 16;
      int blk = ob >> 5;
      int hh = blk / 3, kind = blk % 3;  // 0=q,1=k,2=v
      size_t bh = (size_t)b * 4 + hh;
      float sc = (kind == 0) ? (0.03125f * 1.44269504f) : 1.f;
      #pragma unroll
      for (int j = 0; j < 2; ++j) {
        if (kind < 2) {
          ushort* dst = (kind == 0) ? Qb : (Qb + QSZ);
          int s16 = (t0 >> 4) + wt * 2 + j;
          int eo = s16 * 512 + (((ob & 16) >> 3) + (lg >> 1)) * 128 + lc * 8 + (lg & 1) * 4;
          ushort4 rv;
          rv.x = f2bf(acc[i][j][0] * sc); rv.y = f2bf(acc[i][j][1] * sc);
          rv.z = f2bf(acc[i][j][2] * sc); rv.w = f2bf(acc[i][j][3] * sc);
          *(ushort4*)&dst[bh * 32768 + eo] = rv;
        } else {
          ushort* Vb = Qb + 2 * QSZ;
          int eo = (t0 >> 6) * 2048 + ((ob & 16) >> 4) * 1024
                 + (wt * 4 + j * 2 + (lc >> 3)) * 128 + (lc & 7);
          #pragma unroll
          for (int r = 0; r < 4; ++r)
            Vb[bh * 32768 + eo + (lg * 4 + r) * 8] = f2bf(acc[i][j][r]);
        }
      }
    }
  };

  fragAB afA[2][4], afB[2][4];
  fragC acc[2][2];
  load_af(afA, 0);
  load_af(afB, 64);
  kloop(afA, acc); epi(acc, 0);   load_af(afA, 128);
  kloop(afB, acc); epi(acc, 64);  load_af(afB, 192);
  kloop(afA, acc); epi(acc, 128); load_af(afA, 256);
  kloop(afB, acc); epi(acc, 192); load_af(afB, 320);
  kloop(afA, acc); epi(acc, 256);
  kloop(afB, acc); epi(acc, 320);
}

// ---------------- Fused attention + proj v2: attn9 ----------------
// 512 thr = 8 waves = 4 heads x 2 q-subtiles; 64 q per block; grid 512.
// Each wave runs the FULL s-range (16 iters) for its own 32-q tile -> no
// combine phase at all. K/V L2 traffic halved vs 32-q blocks.
// Then all 8 waves run proj (128o x 64t, k=128) + bias + fp32 residual.
__global__ __launch_bounds__(512) void attn9(
    const ushort* __restrict__ Qb, const ushort* __restrict__ Kb,
    const ushort* __restrict__ Vb, const ushort* __restrict__ wp16,
    const float* __restrict__ bias, const float* __restrict__ resid,
    float* __restrict__ out) {
  __shared__ char arena[33792];
  // [0,16384): Ps per wave 2048B
  // [16384,33792): Olds [64][136] ushort

  int tid = threadIdx.x;
  int w = tid >> 6, lane = tid & 63, lc = lane & 15, lg = lane >> 4;
  int lb = blockIdx.x;
  int gp = (lb & 7) * 64 + (lb >> 3);    // XCD swizzle: 4 b per XCD (2MB K/V set)
  int b = gp >> 4, qp = gp & 15;
  int h = w >> 1, qs = w & 1;
  int bh = b * 4 + h;
  int t0 = qp * 64;
  int qt = qp * 2 + qs;                  // q-tile 0..31

  const ushort* Qg = Qb + (size_t)bh * 32768 + (size_t)qt * 1024 + lane * 8;
  const ushort* Kg = Kb + (size_t)bh * 32768 + lane * 8;
  const ushort* Vg = Vb + (size_t)bh * 32768 + lane * 8;

  fragAB q0 = *(const fragAB*)&Qg[0];
  fragAB q1 = *(const fragAB*)&Qg[512];

  fragC a00 = {0.f,0.f,0.f,0.f}, a01 = {0.f,0.f,0.f,0.f};
  fragC a10 = {0.f,0.f,0.f,0.f}, a11 = {0.f,0.f,0.f,0.f};
  float l0 = 0.f, l1 = 0.f;
  char* PsB = arena + w * 2048;

  for (int i = 0; i < 16; ++i) {
    const ushort* Kt = Kg + i * 2048;
    const ushort* Vt = Vg + i * 2048;
    fragAB kf[4], vf[4];
    #pragma unroll
    for (int j = 0; j < 4; ++j) kf[j] = *(const fragAB*)&Kt[j * 512];
    #pragma unroll
    for (int u = 0; u < 4; ++u) vf[u] = *(const fragAB*)&Vt[u * 512];  // u = cs*2+ks

    #pragma unroll
    for (int ts = 0; ts < 2; ++ts) {
      fragAB qf = ts ? q1 : q0;
      fragC S[4];
      #pragma unroll
      for (int j = 0; j < 4; ++j) {
        fragC z = {0.f,0.f,0.f,0.f};
        S[j] = __builtin_amdgcn_mfma_f32_16x16x32_bf16(kf[j], qf, z, 0, 0, 0);
      }
      float rs = 0.f;
      #pragma unroll
      for (int j = 0; j < 4; ++j) {
        float p0 = __builtin_amdgcn_exp2f(S[j][0]), p1 = __builtin_amdgcn_exp2f(S[j][1]);
        float p2 = __builtin_amdgcn_exp2f(S[j][2]), p3 = __builtin_amdgcn_exp2f(S[j][3]);
        rs += (p0 + p1) + (p2 + p3);
        uint2 wv2;
        wv2.x = pack2(p0, p1);
        wv2.y = pack2(p2, p3);
        int g = j * 2 + (lg >> 1);
        *(uint2*)(PsB + lc * 128 + 16 * (g ^ (lc & 7)) + (lg & 1) * 8) = wv2;
      }
      if (ts) l1 += rs; else l0 += rs;
      fragC* aA = ts ? &a01 : &a00;
      fragC* aB = ts ? &a11 : &a10;
      fragAB bp0 = *(const fragAB*)(PsB + vswz(lc, lg));
      fragAB bp1 = *(const fragAB*)(PsB + vswz(lc, 4 + lg));
      *aA = __builtin_amdgcn_mfma_f32_16x16x32_bf16(vf[0], bp0, *aA, 0, 0, 0);
      *aA = __builtin_amdgcn_mfma_f32_16x16x32_bf16(vf[1], bp1, *aA, 0, 0, 0);
      *aB = __builtin_amdgcn_mfma_f32_16x16x32_bf16(vf[2], bp0, *aB, 0, 0, 0);
      *aB = __builtin_amdgcn_mfma_f32_16x16x32_bf16(vf[3], bp1, *aB, 0, 0, 0);
    }
  }

  // per-wave l reduce (each lane summed a disjoint s-slice)
  l0 += __shfl_xor(l0, 16); l0 += __shfl_xor(l0, 32);
  l1 += __shfl_xor(l1, 16); l1 += __shfl_xor(l1, 32);
  float il0 = 1.f / l0, il1 = 1.f / l1;

  // O (bf16 normalized) -> Olds rows qs*32 + {lc, lc+16}, cols h*32 + ...
  ushort* Olds = (ushort*)(arena + 16384);   // [64][136]
  {
    int rb = qs * 32, cb = h * 32;
    uint2 u;
    u.x = pack2(a00[0] * il0, a00[1] * il0); u.y = pack2(a00[2] * il0, a00[3] * il0);
    *(uint2*)&Olds[(rb + lc) * 136 + cb + lg * 4] = u;
    u.x = pack2(a10[0] * il0, a10[1] * il0); u.y = pack2(a10[2] * il0, a10[3] * il0);
    *(uint2*)&Olds[(rb + lc) * 136 + cb + 16 + lg * 4] = u;
    u.x = pack2(a01[0] * il1, a01[1] * il1); u.y = pack2(a01[2] * il1, a01[3] * il1);
    *(uint2*)&Olds[(rb + lc + 16) * 136 + cb + lg * 4] = u;
    u.x = pack2(a11[0] * il1, a11[1] * il1); u.y = pack2(a11[2] * il1, a11[3] * il1);
    *(uint2*)&Olds[(rb + lc + 16) * 136 + cb + 16 + lg * 4] = u;
  }
  __syncthreads();

  // ---- proj GEMM: out[o,t] = sum_c wp[o,c] * O[t,c] + bias[o] + resid ----
  // wave w owns o rows [16w, 16w+16), all 64 t
  fragC pacc[4] = {{0.f,0.f,0.f,0.f}, {0.f,0.f,0.f,0.f},
                   {0.f,0.f,0.f,0.f}, {0.f,0.f,0.f,0.f}};
  #pragma unroll
  for (int kc = 0; kc < 4; ++kc) {
    fragAB af = *(const fragAB*)&wp16[(size_t)(16 * w + lc) * 128 + kc * 32 + lg * 8];
    #pragma unroll
    for (int j = 0; j < 4; ++j) {
      fragAB bf = *(const fragAB*)&Olds[(j * 16 + lc) * 136 + kc * 32 + lg * 8];
      pacc[j] = __builtin_amdgcn_mfma_f32_16x16x32_bf16(af, bf, pacc[j], 0, 0, 0);
    }
  }
  #pragma unroll
  for (int j = 0; j < 4; ++j) {
    int t = t0 + j * 16 + lc;
    #pragma unroll
    for (int r = 0; r < 4; ++r) {
      int o = 16 * w + lg * 4 + r;
      size_t idx = ((size_t)b * CC + o) * HW + t;
      out[idx] = pacc[j][r] + bias[o] + resid[idx];
    }
  }
}

extern "C" void kernel_launch(void* const* d_in, const int* in_sizes, int n_in,
                              void* d_out, int out_size, void* d_ws, size_t ws_size,
                              hipStream_t stream) {
  (void)in_sizes; (void)n_in; (void)out_size; (void)ws_size;
  const float* x     = (const float*)d_in[0];
  const float* gw    = (const float*)d_in[1];
  const float* gb    = (const float*)d_in[2];
  const float* qkvw  = (const float*)d_in[3];
  const float* projw = (const float*)d_in[4];
  const float* projb = (const float*)d_in[5];
  float* out = (float*)d_out;

  char* wsb = (char*)d_ws;
  ushort* Qb   = (ushort*)(wsb + ((size_t)8 << 20));        // 8 MB (frag-linear)
  ushort* Kb   = Qb + QSZ;                                  // 8 MB (frag-linear)
  ushort* Vb   = Qb + 2 * QSZ;                              // 8 MB (frag-linear)
  ushort* wq16 = (ushort*)(wsb + ((size_t)32 << 20));       // 96 KB
  ushort* wp16 = (ushort*)(wsb + ((size_t)32 << 20) + (128 << 10)); // 32 KB
  float2* stats = (float2*)(wsb + ((size_t)32 << 20) + (256 << 10)); // 8 KB

  gn_stats<<<dim3(BB * NG + 256), 256, 0, stream>>>(x, stats, qkvw, projw, wq16, wp16);
  mgemm_qkv<<<dim3(16, 1, BB), 256, 0, stream>>>(wq16, x, stats, gw, gb, Qb);
  attn9<<<dim3(512), 512, 0, stream>>>(Qb, Kb, Vb, wp16, projb, x, out);
}